// Round 7
// baseline (304.418 us; speedup 1.0000x reference)
//
#include <hip/hip_runtime.h>

// VQ straight-through: B=32, V=4096, D=64, K=512. N = 131072 rows.
// Outputs (flat, concat): z_q_st [N,D] f32, z_q [N,D] f32, indices [N] (as f32).
//
// Correctness contract (passing since R2): replicate numpy fp32 bitwise —
//  - sums of squares (A, C): numpy pairwise_sum scalar 8-accumulator order
//    (acc = d%8, d ascending), products rounded separately (freeze)
//  - z@e.T dots: sequential single-accumulator FMA chain over d=0..63 (BLAS)
//  - d2 = fl(fl(A-2*dot)+C) via fmaf(-2,a,A)+C; argmin = first strict min,
//    k ascending (np.argmin)
//
// R7 design (vs R6: 199us main, VALU time 2.9x FMA floor): register-tiled
// GEMM with lane<->code, wave<->16 rows. The 64-reg array is now acc[16][2]
// (loop-carried accumulators -> compiler CANNOT remat them, unlike the z/e
// inputs it kept reloading in R3-R6). Inner loop re-reads inputs from LDS by
// design: per 4d-step: 8 e ds_read_b32 (stride-65 -> 2-way, free) + 16
// uniform-address z ds_read_b128 (broadcast) + 128 v_fmac. Norms C computed
// in-block per chunk from staged e (single dispatch, no d_ws).

#define VQ_N (32 * 4096)
#define VQ_D 64
#define VQ_K 512
#define CHUNK 128    // codes per LDS chunk (n=2 codes/lane)
#define ESTRIDE 65   // dwords; bank (l+d)%32 for lane l -> 2-way, free
#define ZSTRIDE 68   // dwords; 272 B rows, 16B-aligned for b128

// Rounding barrier: forbids FMA contraction / reassociation through x.
__device__ __forceinline__ float freeze(float x) {
  asm volatile("" : "+v"(x));
  return x;
}

__global__ __launch_bounds__(256) void vq_main_kernel(
    const float* __restrict__ z_e, const float* __restrict__ emb,
    float* __restrict__ out_st, float* __restrict__ out_q,
    float* __restrict__ out_idx) {
  __shared__ float s_e[CHUNK * ESTRIDE];  // 33280 B
  __shared__ float s_z[64 * ZSTRIDE];     // 17408 B
  __shared__ float s_C[CHUNK];            // chunk norms
  __shared__ float s_A[64];               // row norms
  __shared__ int s_best[64];              // best index per row

  const int tid = threadIdx.x;
  const int lane = tid & 63;
  const int w = __builtin_amdgcn_readfirstlane(tid >> 6);  // wave id 0..3
  const int row0 = blockIdx.x * 64;

  // ---- stage the block's 64 z rows into LDS (coalesced f4) ----
  const float4* zg = (const float4*)(z_e + (size_t)row0 * VQ_D);
#pragma unroll
  for (int j = 0; j < 4; ++j) {
    int idx = j * 256 + tid;
    float4 v = zg[idx];
    int r = idx >> 4, c = idx & 15;
    *(float4*)(s_z + r * ZSTRIDE + 4 * c) = v;  // 272r+16c, 16B-aligned
  }

  // per-lane running best across all chunks
  float bv[16];
  int bk[16];
#pragma unroll
  for (int r = 0; r < 16; ++r) { bv[r] = 3.4e38f; bk[r] = 0; }

  const float* zw = s_z + (w * 16) * ZSTRIDE;  // this wave's 16 rows

  for (int c = 0; c < 4; ++c) {  // 4 chunks of 128 codes
    // ---- stage e chunk c: 128 codes x 64 floats (coalesced f4) ----
    const float4* eg = (const float4*)(emb + (size_t)c * CHUNK * VQ_D);
#pragma unroll
    for (int j = 0; j < 8; ++j) {
      int idx = j * 256 + tid;
      float4 v = eg[idx];
      int k = idx >> 4, cc = idx & 15;
      float* p = s_e + k * ESTRIDE + 4 * cc;
      p[0] = v.x; p[1] = v.y; p[2] = v.z; p[3] = v.w;
    }
    __syncthreads();  // s_z (first iter) + s_e ready

    if (c == 0 && w == 0) {
      // ---- A[row] = np.sum(z*z): 8-acc order, rounded products ----
      const float* zz = s_z + lane * ZSTRIDE;
      float q0 = 0.f, q1 = 0.f, q2 = 0.f, q3 = 0.f;
      float q4 = 0.f, q5 = 0.f, q6 = 0.f, q7 = 0.f;
#pragma unroll
      for (int j = 0; j < 16; ++j) {
        float4 v = *(const float4*)(zz + 4 * j);
        if ((j & 1) == 0) {
          q0 += freeze(v.x * v.x); q1 += freeze(v.y * v.y);
          q2 += freeze(v.z * v.z); q3 += freeze(v.w * v.w);
        } else {
          q4 += freeze(v.x * v.x); q5 += freeze(v.y * v.y);
          q6 += freeze(v.z * v.z); q7 += freeze(v.w * v.w);
        }
      }
      s_A[lane] = ((q0 + q1) + (q2 + q3)) + ((q4 + q5) + (q6 + q7));
    }
    if (w == 1) {
      // ---- C[k] = np.sum(e*e) for this chunk (np 8-acc order) ----
#pragma unroll
      for (int j = 0; j < 2; ++j) {
        const float* e = s_e + (j * 64 + lane) * ESTRIDE;
        float r0 = freeze(e[0] * e[0]), r1 = freeze(e[1] * e[1]);
        float r2 = freeze(e[2] * e[2]), r3 = freeze(e[3] * e[3]);
        float r4 = freeze(e[4] * e[4]), r5 = freeze(e[5] * e[5]);
        float r6 = freeze(e[6] * e[6]), r7 = freeze(e[7] * e[7]);
#pragma unroll
        for (int i = 8; i < VQ_D; i += 8) {
          r0 += freeze(e[i + 0] * e[i + 0]); r1 += freeze(e[i + 1] * e[i + 1]);
          r2 += freeze(e[i + 2] * e[i + 2]); r3 += freeze(e[i + 3] * e[i + 3]);
          r4 += freeze(e[i + 4] * e[i + 4]); r5 += freeze(e[i + 5] * e[i + 5]);
          r6 += freeze(e[i + 6] * e[i + 6]); r7 += freeze(e[i + 7] * e[i + 7]);
        }
        s_C[j * 64 + lane] =
            ((r0 + r1) + (r2 + r3)) + ((r4 + r5) + (r6 + r7));
      }
    }

    // ---- d-loop: acc[r][j] += z[r][d] * e[64j+lane][d], d ascending ----
    float acc0[16], acc1[16];
#pragma unroll
    for (int r = 0; r < 16; ++r) { acc0[r] = 0.f; acc1[r] = 0.f; }

    const float* el0 = s_e + lane * ESTRIDE;        // code lane
    const float* el1 = s_e + (64 + lane) * ESTRIDE; // code 64+lane
#pragma unroll
    for (int dd = 0; dd < 16; ++dd) {
      const int d = 4 * dd;
      float e00 = el0[d + 0], e01 = el0[d + 1];
      float e02 = el0[d + 2], e03 = el0[d + 3];
      float e10 = el1[d + 0], e11 = el1[d + 1];
      float e12 = el1[d + 2], e13 = el1[d + 3];
#pragma unroll
      for (int r = 0; r < 16; ++r) {
        float4 zv = *(const float4*)(zw + r * ZSTRIDE + d);  // uniform addr
        float a = acc0[r];
        a = fmaf(zv.x, e00, a); a = fmaf(zv.y, e01, a);
        a = fmaf(zv.z, e02, a); a = fmaf(zv.w, e03, a);
        acc0[r] = a;
        float b = acc1[r];
        b = fmaf(zv.x, e10, b); b = fmaf(zv.y, e11, b);
        b = fmaf(zv.z, e12, b); b = fmaf(zv.w, e13, b);
        acc1[r] = b;
      }
    }

    __syncthreads();  // C(c)/A done; all waves done reading s_e

    // ---- epilogue: fold chunk scores into per-lane running best ----
    const int kg0 = c * CHUNK + lane;
    const int kg1 = kg0 + 64;
    const float C0 = s_C[lane], C1 = s_C[64 + lane];
#pragma unroll
    for (int r = 0; r < 16; ++r) {
      const float Ar = s_A[w * 16 + r];
      float t0 = fmaf(-2.0f, acc0[r], Ar) + C0;
      float t1 = fmaf(-2.0f, acc1[r], Ar) + C1;
      if (t0 < bv[r]) { bv[r] = t0; bk[r] = kg0; }
      if (t1 < bv[r]) { bv[r] = t1; bk[r] = kg1; }
    }
    // next chunk's staging may now overwrite s_e (all reads done; s_C is
    // rewritten only after the next barrier)
  }

  // ---- cross-lane argmin per row: min val, tie -> min index (np.argmin) ----
#pragma unroll
  for (int r = 0; r < 16; ++r) {
    float v = bv[r];
    int b = bk[r];
#pragma unroll
    for (int m = 1; m < 64; m <<= 1) {
      float ov = __shfl_xor(v, m, 64);
      int ob = __shfl_xor(b, m, 64);
      if (ov < v || (ov == v && ob < b)) { v = ov; b = ob; }
    }
    if (lane == 0) s_best[w * 16 + r] = b;
  }
  __syncthreads();

  if (tid < 64) out_idx[row0 + tid] = (float)s_best[tid];

  // ---- coalesced z_q_st / z_q writes: 64 rows x 16 float4 each ----
  const float4* e4v = (const float4*)emb;
  const size_t base4 = (size_t)blockIdx.x * 64 * 16;
  float4* o0 = (float4*)out_st;
  float4* o1 = (float4*)out_q;
#pragma unroll
  for (int t = 0; t < 4; ++t) {
    int i = t * 256 + tid;
    int r = i >> 4, j = i & 15;
    float4 v = e4v[s_best[r] * 16 + j];
    o0[base4 + i] = v;
    o1[base4 + i] = v;
  }
}

extern "C" void kernel_launch(void* const* d_in, const int* in_sizes, int n_in,
                              void* d_out, int out_size, void* d_ws,
                              size_t ws_size, hipStream_t stream) {
  const float* z_e = (const float*)d_in[0];  // [N, D] fp32
  const float* emb = (const float*)d_in[1];  // [K, D] fp32

  float* out_st = (float*)d_out;                 // [N, D]
  float* out_q = out_st + (size_t)VQ_N * VQ_D;   // [N, D]
  float* out_idx = out_q + (size_t)VQ_N * VQ_D;  // [N] as float

  vq_main_kernel<<<VQ_N / 64, 256, 0, stream>>>(z_e, emb, out_st, out_q,
                                                out_idx);
}